// Round 1
// baseline (120.745 us; speedup 1.0000x reference)
//
#include <hip/hip_runtime.h>

#define NB 8
#define NN 512
#define DD 64
#define NCLS 4

// One wave per (b,v); lane = feature dim e (also output dim d in epilogue).
// Block = 256 threads = 4 waves. Grid = NB*NN/4 = 1024 blocks.
__global__ __launch_bounds__(256) void msg_kernel(
    const float* __restrict__ h,     // [B,N,D]
    const int*   __restrict__ adj,   // [B,N,N]
    const float* __restrict__ Min,   // [C,D,D]
    const float* __restrict__ Mout,  // [C,D,D]
    const float* __restrict__ bias,  // [2D]
    float* __restrict__ out)         // [B,N,2D]
{
    __shared__ __align__(16) float S[4][2][NCLS][DD];

    const int lane  = threadIdx.x & 63;
    const int wslot = threadIdx.x >> 6;
    const int wid   = blockIdx.x * 4 + wslot;
    const int b     = wid >> 9;          // wid / 512
    const int v     = wid & (NN - 1);    // wid % 512

    const float* hb   = h   + (size_t)b * NN * DD;
    const int*   adjb = adj + (size_t)b * NN * NN;

    // Bucket accumulators. S[0] derived from total: S0 = tot - S1 - S2 - S3.
    float tot  = 0.f;
    float ain1 = 0.f, ain2 = 0.f, ain3 = 0.f;
    float aout1 = 0.f, aout2 = 0.f, aout3 = 0.f;

    for (int w0 = 0; w0 < NN; w0 += 64) {
        // lane-parallel adjacency chunk loads (row for 'in', column for 'out')
        int cin_chunk  = adjb[v * NN + (w0 + lane)];
        int cout_chunk = adjb[(w0 + lane) * NN + v];
        #pragma unroll
        for (int k = 0; k < 64; ++k) {
            float hw  = hb[(w0 + k) * DD + lane];          // coalesced 256B
            int   cin  = __builtin_amdgcn_readlane(cin_chunk,  k);  // SGPR
            int   cout = __builtin_amdgcn_readlane(cout_chunk, k);  // SGPR
            tot += hw;
            ain1  = fmaf((cin  == 1) ? 1.f : 0.f, hw, ain1);
            ain2  = fmaf((cin  == 2) ? 1.f : 0.f, hw, ain2);
            ain3  = fmaf((cin  == 3) ? 1.f : 0.f, hw, ain3);
            aout1 = fmaf((cout == 1) ? 1.f : 0.f, hw, aout1);
            aout2 = fmaf((cout == 2) ? 1.f : 0.f, hw, aout2);
            aout3 = fmaf((cout == 3) ? 1.f : 0.f, hw, aout3);
        }
    }
    float ain0  = tot - ain1  - ain2  - ain3;
    float aout0 = tot - aout1 - aout2 - aout3;

    // Stash per-wave bucket sums: S[wslot][dir][c][e=lane]
    S[wslot][0][0][lane] = ain0;
    S[wslot][0][1][lane] = ain1;
    S[wslot][0][2][lane] = ain2;
    S[wslot][0][3][lane] = ain3;
    S[wslot][1][0][lane] = aout0;
    S[wslot][1][1][lane] = aout1;
    S[wslot][1][2][lane] = aout2;
    S[wslot][1][3][lane] = aout3;
    __syncthreads();

    // Epilogue: msg[d=lane] = sum_{c,e} M[c][d][e] * S[dir][c][e]
    // Matrix rows gathered from global (16KB each, L1/L2-hot); S read as LDS broadcast.
    float o_in = 0.f, o_out = 0.f;
    #pragma unroll
    for (int c = 0; c < NCLS; ++c) {
        #pragma unroll
        for (int e0 = 0; e0 < DD; e0 += 4) {
            float4 mi = *reinterpret_cast<const float4*>(&Min [(c * DD + lane) * DD + e0]);
            float4 mo = *reinterpret_cast<const float4*>(&Mout[(c * DD + lane) * DD + e0]);
            float4 si = *reinterpret_cast<const float4*>(&S[wslot][0][c][e0]);
            float4 so = *reinterpret_cast<const float4*>(&S[wslot][1][c][e0]);
            o_in  = fmaf(mi.x, si.x, o_in);
            o_in  = fmaf(mi.y, si.y, o_in);
            o_in  = fmaf(mi.z, si.z, o_in);
            o_in  = fmaf(mi.w, si.w, o_in);
            o_out = fmaf(mo.x, so.x, o_out);
            o_out = fmaf(mo.y, so.y, o_out);
            o_out = fmaf(mo.z, so.z, o_out);
            o_out = fmaf(mo.w, so.w, o_out);
        }
    }

    float* ov = out + (size_t)(b * NN + v) * (2 * DD);
    ov[lane]      = o_in  + bias[lane];
    ov[DD + lane] = o_out + bias[DD + lane];
}

extern "C" void kernel_launch(void* const* d_in, const int* in_sizes, int n_in,
                              void* d_out, int out_size, void* d_ws, size_t ws_size,
                              hipStream_t stream) {
    const float* node_state = (const float*)d_in[0];  // [8,512,64]
    const int*   adj_mat    = (const int*)  d_in[1];  // [8,512,512]
    const float* matrix_in  = (const float*)d_in[2];  // [4,64,64]
    const float* matrix_out = (const float*)d_in[3];  // [4,64,64]
    const float* bias       = (const float*)d_in[4];  // [128]
    float* out = (float*)d_out;                       // [8,512,128]

    dim3 grid(NB * NN / 4);   // 1024 blocks, 4 waves each
    dim3 block(256);
    msg_kernel<<<grid, block, 0, stream>>>(node_state, adj_mat, matrix_in,
                                           matrix_out, bias, out);
}

// Round 2
// 26.114 us; speedup vs baseline: 4.6238x; 4.6238x over previous
//
#include <hip/hip_runtime.h>

#define NB 8
#define NN 512
#define DD 64
#define NCLS 4

typedef short bf16x8 __attribute__((ext_vector_type(8)));
typedef float f32x4 __attribute__((ext_vector_type(4)));

__device__ __forceinline__ unsigned short f2bf(float f) {
    unsigned int x = __builtin_bit_cast(unsigned int, f);
    x += 0x7FFFu + ((x >> 16) & 1u);      // round-to-nearest-even (finite inputs)
    return (unsigned short)(x >> 16);
}

__device__ __forceinline__ void gload_lds16(const void* g, void* lds) {
    __builtin_amdgcn_global_load_lds(
        (const __attribute__((address_space(1))) unsigned int*)g,
        (__attribute__((address_space(3))) unsigned int*)lds, 16, 0, 0);
}

// one-hot A-fragment: 8 adjacency ints -> 8 bf16 (1.0 where ==cls)
__device__ __forceinline__ bf16x8 onehot8(int4 a0, int4 a1, int cls) {
    union { unsigned int u[4]; bf16x8 v; } r;
    r.u[0] = (a0.x == cls ? 0x3F80u : 0u) | (a0.y == cls ? 0x3F800000u : 0u);
    r.u[1] = (a0.z == cls ? 0x3F80u : 0u) | (a0.w == cls ? 0x3F800000u : 0u);
    r.u[2] = (a1.x == cls ? 0x3F80u : 0u) | (a1.y == cls ? 0x3F800000u : 0u);
    r.u[3] = (a1.z == cls ? 0x3F80u : 0u) | (a1.w == cls ? 0x3F800000u : 0u);
    return r.v;
}

// ---------------- prepass: adjT, HT_bf, W_bf ----------------
__global__ __launch_bounds__(256) void prep_kernel(
    const float* __restrict__ h, const int* __restrict__ adj,
    const float* __restrict__ Min, const float* __restrict__ Mout,
    int* __restrict__ adjT, unsigned short* __restrict__ HTbf,
    unsigned short* __restrict__ Wbf)
{
    const int blk = blockIdx.x, t = threadIdx.x;
    if (blk < 512) {                       // adjT[b][v][w] = adj[b][w][v]
        __shared__ int tile[64][65];
        const int b = blk >> 6;
        const int tr = ((blk >> 3) & 7) * 64, tc = (blk & 7) * 64;
        const int* src = adj + (size_t)b * NN * NN;
        int* dst = adjT + (size_t)b * NN * NN;
        #pragma unroll
        for (int i = 0; i < 16; ++i) {
            int idx = i * 256 + t, r = idx >> 6, cc = idx & 63;
            tile[r][cc] = src[(tr + r) * NN + tc + cc];
        }
        __syncthreads();
        #pragma unroll
        for (int i = 0; i < 16; ++i) {
            int idx = i * 256 + t, r = idx >> 6, cc = idx & 63;
            dst[(tc + r) * NN + tr + cc] = tile[cc][r];
        }
    } else if (blk < 512 + 1024) {         // HTbf[b][e][w] = bf16(h[b][w][e])
        int idx = (blk - 512) * 256 + t;
        int w = idx & 511, e = (idx >> 9) & 63, b = idx >> 15;
        HTbf[((size_t)b * DD + e) * NN + w] = f2bf(h[((size_t)b * NN + w) * DD + e]);
    } else {                               // Wbf[dir][d][c*64+e] = bf16(M[c][d][e])
        int idx = (blk - 1536) * 256 + t;
        int dir = idx >> 14, d = (idx >> 8) & 63, k = idx & 255;
        int c = k >> 6, e = k & 63;
        const float* M = dir ? Mout : Min;
        Wbf[idx] = f2bf(M[(c * DD + d) * DD + e]);
    }
}

// ---------------- main: one-hot MFMA ----------------
// block: (b, 8 v's). 4 waves = (dir, row-tile). K=512 in 4 chunks of 128, dbuf.
__global__ __launch_bounds__(256) void msg_mfma_kernel(
    const int* __restrict__ adj, const int* __restrict__ adjT,
    const unsigned short* __restrict__ HTbf, const unsigned short* __restrict__ Wbf,
    const float* __restrict__ bias, float* __restrict__ out)
{
    __shared__ unsigned short HT[2][DD][128];      // 2 x 16 KB, swizzled image
    __shared__ unsigned short S2[2][8][NCLS * DD]; // 8 KB, swizzled rows

    const int t = threadIdx.x;
    const int lane = t & 63, wv = t >> 6;
    const int dir = wv >> 1, rt = wv & 1;
    const int b = blockIdx.x >> 6;
    const int v0 = (blockIdx.x & 63) * 8;
    const int r = lane & 15, kb = lane >> 4;

    const int* adjsrc = (dir ? adjT : adj) + (size_t)b * NN * NN;
    const unsigned short* HTg = HTbf + (size_t)b * DD * NN;

    // stage chunk c0 (w in [c0*128, c0*128+128)) into buffer s.
    // LDS linear; source pre-swizzled so reads can XOR-deswizzle (T2 via m173).
    auto stage = [&](int s, int c0) {
        #pragma unroll
        for (int q = 0; q < 4; ++q) {
            int L = wv * 4 + q;
            int e = 4 * L + (lane >> 4);
            int off = ((lane & 15) << 4) ^ ((e & 7) << 4);   // byte off in 256B row
            const unsigned short* src = HTg + e * NN + c0 * 128 + (off >> 1);
            gload_lds16(src, &HT[s][4 * L][0]);
        }
    };

    stage(0, 0);
    __syncthreads();

    // ---- phase 1: S[(v,c),e] = sum_w onehot * h ----
    f32x4 acc[4] = {f32x4{0,0,0,0}, f32x4{0,0,0,0}, f32x4{0,0,0,0}, f32x4{0,0,0,0}};
    const int vloc = rt * 4 + (r >> 2);   // this lane's A-row -> v (0..7)
    const int cls  = r & 3;               // and class
    const int* arow = adjsrc + (v0 + vloc) * NN + 8 * kb;

    for (int c = 0; c < 4; ++c) {
        int s = c & 1;
        if (c < 3) stage(s ^ 1, c + 1);   // prefetch next chunk (overlaps MFMA)
        #pragma unroll
        for (int kc = 0; kc < 4; ++kc) {
            int k0 = c * 128 + kc * 32;
            int4 a0 = *(const int4*)(arow + k0);
            int4 a1 = *(const int4*)(arow + k0 + 4);
            bf16x8 afrag = onehot8(a0, a1, cls);
            #pragma unroll
            for (int n = 0; n < 4; ++n) {
                int e = n * 16 + r;
                int boff = (kc * 64 + (kb << 4)) ^ ((e & 7) << 4);
                bf16x8 bfrag = *(const bf16x8*)((const char*)&HT[s][e][0] + boff);
                acc[n] = __builtin_amdgcn_mfma_f32_16x16x32_bf16(afrag, bfrag, acc[n], 0, 0, 0);
            }
        }
        __syncthreads();   // drains prefetch + protects buffer reuse
    }

    // ---- S -> LDS (bf16, XOR-swizzled rows). D layout: col=lane&15, row=kb*4+reg ----
    #pragma unroll
    for (int ct = 0; ct < 4; ++ct) {
        #pragma unroll
        for (int rg = 0; rg < 4; ++rg) {
            int row_g = rt * 16 + kb * 4 + rg;        // 0..31 = (v,c)
            int vv = row_g >> 2, cc2 = row_g & 3;
            int e = ct * 16 + r;
            int rb = (cc2 * 128 + e * 2) ^ ((vv & 7) << 4);
            *(unsigned short*)((char*)&S2[dir][vv][0] + rb) = f2bf(acc[ct][rg]);
        }
    }
    __syncthreads();

    // ---- phase 2: out[v, dir*64+d] = sum_{c,e} S[v,(c,e)] * W[(c,e),d] + bias ----
    f32x4 acc2[2] = {f32x4{0,0,0,0}, f32x4{0,0,0,0}};
    #pragma unroll
    for (int kc = 0; kc < 8; ++kc) {
        int vv = r & 7;                               // A rows 8..15 duplicate 0..7
        int kbase = kc * 32 + kb * 8;
        int rb = (kbase * 2) ^ (vv << 4);
        bf16x8 a2 = *(const bf16x8*)((const char*)&S2[dir][vv][0] + rb);
        #pragma unroll
        for (int j = 0; j < 2; ++j) {
            int d = (rt * 2 + j) * 16 + r;
            bf16x8 b2 = *(const bf16x8*)&Wbf[(dir * DD + d) * 256 + kbase];
            acc2[j] = __builtin_amdgcn_mfma_f32_16x16x32_bf16(a2, b2, acc2[j], 0, 0, 0);
        }
    }
    #pragma unroll
    for (int j = 0; j < 2; ++j) {
        int d = (rt * 2 + j) * 16 + r;
        float bs = bias[dir * DD + d];
        #pragma unroll
        for (int rg = 0; rg < 4; ++rg) {
            int row = kb * 4 + rg;                    // duplicated rows >=8 skipped
            if (row < 8)
                out[((size_t)(b * NN + v0 + row)) * (2 * DD) + dir * DD + d] = acc2[j][rg] + bs;
        }
    }
}

// ---------------- fallback (R1 kernel, used only if ws too small) ----------------
__global__ __launch_bounds__(256) void msg_kernel(
    const float* __restrict__ h, const int* __restrict__ adj,
    const float* __restrict__ Min, const float* __restrict__ Mout,
    const float* __restrict__ bias, float* __restrict__ out)
{
    __shared__ __align__(16) float S[4][2][NCLS][DD];
    const int lane = threadIdx.x & 63, wslot = threadIdx.x >> 6;
    const int wid = blockIdx.x * 4 + wslot;
    const int b = wid >> 9, v = wid & (NN - 1);
    const float* hb = h + (size_t)b * NN * DD;
    const int* adjb = adj + (size_t)b * NN * NN;
    float tot = 0.f, ain1 = 0.f, ain2 = 0.f, ain3 = 0.f, aout1 = 0.f, aout2 = 0.f, aout3 = 0.f;
    for (int w0 = 0; w0 < NN; w0 += 64) {
        int cin_chunk = adjb[v * NN + (w0 + lane)];
        int cout_chunk = adjb[(w0 + lane) * NN + v];
        #pragma unroll
        for (int k = 0; k < 64; ++k) {
            float hw = hb[(w0 + k) * DD + lane];
            int cin = __builtin_amdgcn_readlane(cin_chunk, k);
            int cout = __builtin_amdgcn_readlane(cout_chunk, k);
            tot += hw;
            ain1 = fmaf((cin == 1) ? 1.f : 0.f, hw, ain1);
            ain2 = fmaf((cin == 2) ? 1.f : 0.f, hw, ain2);
            ain3 = fmaf((cin == 3) ? 1.f : 0.f, hw, ain3);
            aout1 = fmaf((cout == 1) ? 1.f : 0.f, hw, aout1);
            aout2 = fmaf((cout == 2) ? 1.f : 0.f, hw, aout2);
            aout3 = fmaf((cout == 3) ? 1.f : 0.f, hw, aout3);
        }
    }
    S[wslot][0][0][lane] = tot - ain1 - ain2 - ain3;
    S[wslot][0][1][lane] = ain1; S[wslot][0][2][lane] = ain2; S[wslot][0][3][lane] = ain3;
    S[wslot][1][0][lane] = tot - aout1 - aout2 - aout3;
    S[wslot][1][1][lane] = aout1; S[wslot][1][2][lane] = aout2; S[wslot][1][3][lane] = aout3;
    __syncthreads();
    float o_in = 0.f, o_out = 0.f;
    #pragma unroll
    for (int c = 0; c < NCLS; ++c)
        for (int e0 = 0; e0 < DD; e0 += 4) {
            float4 mi = *reinterpret_cast<const float4*>(&Min[(c * DD + lane) * DD + e0]);
            float4 mo = *reinterpret_cast<const float4*>(&Mout[(c * DD + lane) * DD + e0]);
            float4 si = *reinterpret_cast<const float4*>(&S[wslot][0][c][e0]);
            float4 so = *reinterpret_cast<const float4*>(&S[wslot][1][c][e0]);
            o_in = fmaf(mi.x, si.x, fmaf(mi.y, si.y, fmaf(mi.z, si.z, fmaf(mi.w, si.w, o_in))));
            o_out = fmaf(mo.x, so.x, fmaf(mo.y, so.y, fmaf(mo.z, so.z, fmaf(mo.w, so.w, o_out))));
        }
    float* ov = out + (size_t)(b * NN + v) * (2 * DD);
    ov[lane] = o_in + bias[lane];
    ov[DD + lane] = o_out + bias[DD + lane];
}

extern "C" void kernel_launch(void* const* d_in, const int* in_sizes, int n_in,
                              void* d_out, int out_size, void* d_ws, size_t ws_size,
                              hipStream_t stream) {
    const float* node_state = (const float*)d_in[0];
    const int*   adj_mat    = (const int*)  d_in[1];
    const float* matrix_in  = (const float*)d_in[2];
    const float* matrix_out = (const float*)d_in[3];
    const float* bias       = (const float*)d_in[4];
    float* out = (float*)d_out;

    const size_t ADJT_OFF = 0;
    const size_t HT_OFF = (size_t)NB * NN * NN * 4;            // 8 MB
    const size_t W_OFF  = HT_OFF + (size_t)NB * DD * NN * 2;   // +512 KB
    const size_t NEED   = W_OFF + (size_t)2 * DD * 256 * 2;    // +64 KB

    if (ws_size < NEED) {   // scratch too small: proven-correct R1 path
        msg_kernel<<<NB * NN / 4, 256, 0, stream>>>(node_state, adj_mat, matrix_in,
                                                    matrix_out, bias, out);
        return;
    }
    int* adjT = (int*)((char*)d_ws + ADJT_OFF);
    unsigned short* HTbf = (unsigned short*)((char*)d_ws + HT_OFF);
    unsigned short* Wbf  = (unsigned short*)((char*)d_ws + W_OFF);

    prep_kernel<<<1664, 256, 0, stream>>>(node_state, adj_mat, matrix_in, matrix_out,
                                          adjT, HTbf, Wbf);
    msg_mfma_kernel<<<NB * NN / 8, 256, 0, stream>>>(adj_mat, adjT, HTbf, Wbf, bias, out);
}

// Round 3
// 22.046 us; speedup vs baseline: 5.4769x; 1.1845x over previous
//
#include <hip/hip_runtime.h>

#define NB 8
#define NN 512
#define DD 64
#define NCLS 4

typedef short bf16x8 __attribute__((ext_vector_type(8)));
typedef float f32x4 __attribute__((ext_vector_type(4)));

__device__ __forceinline__ unsigned short f2bf(float f) {
    unsigned int x = __builtin_bit_cast(unsigned int, f);
    x += 0x7FFFu + ((x >> 16) & 1u);      // round-to-nearest-even (finite inputs)
    return (unsigned short)(x >> 16);
}

__device__ __forceinline__ void gload_lds16(const void* g, void* lds) {
    __builtin_amdgcn_global_load_lds(
        (const __attribute__((address_space(1))) unsigned int*)g,
        (__attribute__((address_space(3))) unsigned int*)lds, 16, 0, 0);
}

// one-hot A-fragment from 16 packed bits: elem i = 1.0bf16 if ((bits>>2i)&3)==cls
__device__ __forceinline__ bf16x8 onehot_packed(unsigned int bits, unsigned int cls) {
    union { unsigned int u[4]; bf16x8 v; } r;
    #pragma unroll
    for (int j = 0; j < 4; ++j) {
        unsigned int c0 = (bits >> (4 * j)) & 3u;
        unsigned int c1 = (bits >> (4 * j + 2)) & 3u;
        r.u[j] = (c0 == cls ? 0x3F80u : 0u) | (c1 == cls ? 0x3F800000u : 0u);
    }
    return r.v;
}

// ---------------- prep: 2-bit packed adj (both orientations), HT bf16, W bf16 ----
__global__ __launch_bounds__(256) void prep_kernel(
    const float* __restrict__ h, const int* __restrict__ adj,
    const float* __restrict__ Min, const float* __restrict__ Mout,
    unsigned int* __restrict__ packR, unsigned int* __restrict__ packC,
    unsigned short* __restrict__ HTbf, unsigned short* __restrict__ Wbf)
{
    const int blk = blockIdx.x, t = threadIdx.x;
    if (blk < 64) {                        // row-pack: packR[b][v] = 32 u32 (2b/edge)
        const int b = blk >> 3, r0 = (blk & 7) * 64;
        #pragma unroll
        for (int i = 0; i < 8; ++i) {
            int idx = i * 256 + t;
            int row = r0 + (idx >> 5), pk = idx & 31;
            const int* src = adj + ((size_t)b * NN + row) * NN + pk * 16;
            unsigned int u = 0;
            #pragma unroll
            for (int j = 0; j < 16; ++j) u |= ((unsigned int)src[j] & 3u) << (2 * j);
            packR[((size_t)b * NN + row) * 32 + pk] = u;
        }
    } else if (blk < 576) {                // col-pack via 64x64 LDS tile transpose
        __shared__ int tile[64][65];
        __shared__ __align__(16) unsigned int tp[64][4];
        const int bb = blk - 64;
        const int b = bb >> 6, tr = ((bb >> 3) & 7) * 64, tc = (bb & 7) * 64;
        const int* src = adj + (size_t)b * NN * NN;
        #pragma unroll
        for (int i = 0; i < 16; ++i) {
            int idx = i * 256 + t, rr = idx >> 6, cc = idx & 63;
            tile[rr][cc] = src[(size_t)(tr + rr) * NN + tc + cc];
        }
        __syncthreads();
        {
            int row = t & 63, part = t >> 6;   // row = orig col (output v)
            unsigned int u = 0;
            #pragma unroll
            for (int j = 0; j < 16; ++j)
                u |= ((unsigned int)tile[part * 16 + j][row] & 3u) << (2 * j);
            tp[row][part] = u;
        }
        __syncthreads();
        if (t < 64)
            *(uint4*)&packC[((size_t)b * NN + tc + t) * 32 + (tr >> 4)] =
                *(const uint4*)&tp[t][0];
    } else if (blk < 640) {                // HTbf[b][e][w] = bf16(h[b][w][e])
        const int bb = blk - 576;
        #pragma unroll
        for (int i = 0; i < 16; ++i) {
            int idx = bb * 4096 + i * 256 + t;
            int w = idx & 511, e = (idx >> 9) & 63, b = idx >> 15;
            HTbf[((size_t)b * DD + e) * NN + w] = f2bf(h[((size_t)b * NN + w) * DD + e]);
        }
    } else {                               // Wbf[dir][d][c*64+e] = bf16(M[c][d][e])
        int idx = (blk - 640) * 256 + t;
        int dir = idx >> 14, d = (idx >> 8) & 63, k = idx & 255;
        int c = k >> 6, e = k & 63;
        const float* M = dir ? Mout : Min;
        Wbf[idx] = f2bf(M[(c * DD + d) * DD + e]);
    }
}

// ---------------- main: one-hot MFMA from packed bits ----------------
// block: (b, 8 v's). 4 waves = (dir, row-tile). K=512 in 4 chunks of 128, dbuf.
__global__ __launch_bounds__(256) void msg_mfma_kernel(
    const unsigned int* __restrict__ packR, const unsigned int* __restrict__ packC,
    const unsigned short* __restrict__ HTbf, const unsigned short* __restrict__ Wbf,
    const float* __restrict__ bias, float* __restrict__ out)
{
    __shared__ unsigned short HT[2][DD][128];      // 2 x 16 KB, swizzled image
    __shared__ unsigned short S2[2][8][NCLS * DD]; // 8 KB, swizzled rows

    const int t = threadIdx.x;
    const int lane = t & 63, wv = t >> 6;
    const int dir = wv >> 1, rt = wv & 1;
    const int b = blockIdx.x >> 6;
    const int v0 = (blockIdx.x & 63) * 8;
    const int r = lane & 15, kb = lane >> 4;

    const unsigned short* HTg = HTbf + (size_t)b * DD * NN;

    auto stage = [&](int s, int c0) {
        #pragma unroll
        for (int q = 0; q < 4; ++q) {
            int L = wv * 4 + q;
            int e = 4 * L + (lane >> 4);
            int off = ((lane & 15) << 4) ^ ((e & 7) << 4);   // byte off in 256B row
            const unsigned short* src = HTg + e * NN + c0 * 128 + (off >> 1);
            gload_lds16(src, &HT[s][4 * L][0]);
        }
    };

    stage(0, 0);

    // A-operand bits: lane covers (vloc, cls); u16 per (chunk, kc) = 8 edges
    const int vloc = rt * 4 + (r >> 2);
    const unsigned int cls = (unsigned int)(r & 3);
    const unsigned short* prow = (const unsigned short*)(
        (dir ? packC : packR) + ((size_t)b * NN + v0 + vloc) * 32);
    unsigned int bits0  = prow[kb];        unsigned int bits1  = prow[4 + kb];
    unsigned int bits2  = prow[8 + kb];    unsigned int bits3  = prow[12 + kb];
    unsigned int bits4  = prow[16 + kb];   unsigned int bits5  = prow[20 + kb];
    unsigned int bits6  = prow[24 + kb];   unsigned int bits7  = prow[28 + kb];
    unsigned int bits8  = prow[32 + kb];   unsigned int bits9  = prow[36 + kb];
    unsigned int bits10 = prow[40 + kb];   unsigned int bits11 = prow[44 + kb];
    unsigned int bits12 = prow[48 + kb];   unsigned int bits13 = prow[52 + kb];
    unsigned int bits14 = prow[56 + kb];   unsigned int bits15 = prow[60 + kb];

    __syncthreads();

    // ---- phase 1: S[(v,c),e] = sum_w onehot * h ----
    f32x4 acc[4] = {f32x4{0,0,0,0}, f32x4{0,0,0,0}, f32x4{0,0,0,0}, f32x4{0,0,0,0}};
    #pragma unroll
    for (int c = 0; c < 4; ++c) {
        int s = c & 1;
        if (c < 3) stage(s ^ 1, c + 1);   // prefetch next chunk (overlaps MFMA)
        #pragma unroll
        for (int kc = 0; kc < 4; ++kc) {
            unsigned int bits;
            switch (c * 4 + kc) {         // compile-time after unroll
                case 0:  bits = bits0;  break;  case 1:  bits = bits1;  break;
                case 2:  bits = bits2;  break;  case 3:  bits = bits3;  break;
                case 4:  bits = bits4;  break;  case 5:  bits = bits5;  break;
                case 6:  bits = bits6;  break;  case 7:  bits = bits7;  break;
                case 8:  bits = bits8;  break;  case 9:  bits = bits9;  break;
                case 10: bits = bits10; break;  case 11: bits = bits11; break;
                case 12: bits = bits12; break;  case 13: bits = bits13; break;
                case 14: bits = bits14; break;  default: bits = bits15; break;
            }
            bf16x8 afrag = onehot_packed(bits, cls);
            #pragma unroll
            for (int n = 0; n < 4; ++n) {
                int e = n * 16 + r;
                int boff = (kc * 64 + (kb << 4)) ^ ((e & 7) << 4);
                bf16x8 bfrag = *(const bf16x8*)((const char*)&HT[s][e][0] + boff);
                acc[n] = __builtin_amdgcn_mfma_f32_16x16x32_bf16(afrag, bfrag, acc[n], 0, 0, 0);
            }
        }
        __syncthreads();   // drains prefetch + protects buffer reuse
    }

    // ---- S -> LDS (bf16, XOR-swizzled rows). D layout: col=lane&15, row=kb*4+reg ----
    #pragma unroll
    for (int ct = 0; ct < 4; ++ct) {
        #pragma unroll
        for (int rg = 0; rg < 4; ++rg) {
            int row_g = rt * 16 + kb * 4 + rg;        // 0..31 = (v,c)
            int vv = row_g >> 2, cc2 = row_g & 3;
            int e = ct * 16 + r;
            int rb = (cc2 * 128 + e * 2) ^ ((vv & 7) << 4);
            *(unsigned short*)((char*)&S2[dir][vv][0] + rb) = f2bf(acc[ct][rg]);
        }
    }
    __syncthreads();

    // ---- phase 2: out[v, dir*64+d] = sum_{c,e} S[v,(c,e)] * W[(c,e),d] + bias ----
    f32x4 acc2[2] = {f32x4{0,0,0,0}, f32x4{0,0,0,0}};
    #pragma unroll
    for (int kc = 0; kc < 8; ++kc) {
        int vv = r & 7;                               // A rows 8..15 duplicate 0..7
        int kbase = kc * 32 + kb * 8;
        int rb = (kbase * 2) ^ (vv << 4);
        bf16x8 a2 = *(const bf16x8*)((const char*)&S2[dir][vv][0] + rb);
        #pragma unroll
        for (int j = 0; j < 2; ++j) {
            int d = (rt * 2 + j) * 16 + r;
            bf16x8 b2 = *(const bf16x8*)&Wbf[(dir * DD + d) * 256 + kbase];
            acc2[j] = __builtin_amdgcn_mfma_f32_16x16x32_bf16(a2, b2, acc2[j], 0, 0, 0);
        }
    }
    #pragma unroll
    for (int j = 0; j < 2; ++j) {
        int d = (rt * 2 + j) * 16 + r;
        float bs = bias[dir * DD + d];
        #pragma unroll
        for (int rg = 0; rg < 4; ++rg) {
            int row = kb * 4 + rg;                    // duplicated rows >=8 skipped
            if (row < 8)
                out[((size_t)(b * NN + v0 + row)) * (2 * DD) + dir * DD + d] = acc2[j][rg] + bs;
        }
    }
}

// ---------------- fallback (R1 kernel, used only if ws too small) ----------------
__global__ __launch_bounds__(256) void msg_kernel(
    const float* __restrict__ h, const int* __restrict__ adj,
    const float* __restrict__ Min, const float* __restrict__ Mout,
    const float* __restrict__ bias, float* __restrict__ out)
{
    __shared__ __align__(16) float S[4][2][NCLS][DD];
    const int lane = threadIdx.x & 63, wslot = threadIdx.x >> 6;
    const int wid = blockIdx.x * 4 + wslot;
    const int b = wid >> 9, v = wid & (NN - 1);
    const float* hb = h + (size_t)b * NN * DD;
    const int* adjb = adj + (size_t)b * NN * NN;
    float tot = 0.f, ain1 = 0.f, ain2 = 0.f, ain3 = 0.f, aout1 = 0.f, aout2 = 0.f, aout3 = 0.f;
    for (int w0 = 0; w0 < NN; w0 += 64) {
        int cin_chunk = adjb[v * NN + (w0 + lane)];
        int cout_chunk = adjb[(w0 + lane) * NN + v];
        #pragma unroll
        for (int k = 0; k < 64; ++k) {
            float hw = hb[(w0 + k) * DD + lane];
            int cin = __builtin_amdgcn_readlane(cin_chunk, k);
            int cout = __builtin_amdgcn_readlane(cout_chunk, k);
            tot += hw;
            ain1 = fmaf((cin == 1) ? 1.f : 0.f, hw, ain1);
            ain2 = fmaf((cin == 2) ? 1.f : 0.f, hw, ain2);
            ain3 = fmaf((cin == 3) ? 1.f : 0.f, hw, ain3);
            aout1 = fmaf((cout == 1) ? 1.f : 0.f, hw, aout1);
            aout2 = fmaf((cout == 2) ? 1.f : 0.f, hw, aout2);
            aout3 = fmaf((cout == 3) ? 1.f : 0.f, hw, aout3);
        }
    }
    S[wslot][0][0][lane] = tot - ain1 - ain2 - ain3;
    S[wslot][0][1][lane] = ain1; S[wslot][0][2][lane] = ain2; S[wslot][0][3][lane] = ain3;
    S[wslot][1][0][lane] = tot - aout1 - aout2 - aout3;
    S[wslot][1][1][lane] = aout1; S[wslot][1][2][lane] = aout2; S[wslot][1][3][lane] = aout3;
    __syncthreads();
    float o_in = 0.f, o_out = 0.f;
    #pragma unroll
    for (int c = 0; c < NCLS; ++c)
        for (int e0 = 0; e0 < DD; e0 += 4) {
            float4 mi = *reinterpret_cast<const float4*>(&Min[(c * DD + lane) * DD + e0]);
            float4 mo = *reinterpret_cast<const float4*>(&Mout[(c * DD + lane) * DD + e0]);
            float4 si = *reinterpret_cast<const float4*>(&S[wslot][0][c][e0]);
            float4 so = *reinterpret_cast<const float4*>(&S[wslot][1][c][e0]);
            o_in = fmaf(mi.x, si.x, fmaf(mi.y, si.y, fmaf(mi.z, si.z, fmaf(mi.w, si.w, o_in))));
            o_out = fmaf(mo.x, so.x, fmaf(mo.y, so.y, fmaf(mo.z, so.z, fmaf(mo.w, so.w, o_out))));
        }
    float* ov = out + (size_t)(b * NN + v) * (2 * DD);
    ov[lane] = o_in + bias[lane];
    ov[DD + lane] = o_out + bias[DD + lane];
}

extern "C" void kernel_launch(void* const* d_in, const int* in_sizes, int n_in,
                              void* d_out, int out_size, void* d_ws, size_t ws_size,
                              hipStream_t stream) {
    const float* node_state = (const float*)d_in[0];
    const int*   adj_mat    = (const int*)  d_in[1];
    const float* matrix_in  = (const float*)d_in[2];
    const float* matrix_out = (const float*)d_in[3];
    const float* bias       = (const float*)d_in[4];
    float* out = (float*)d_out;

    const size_t PACKR_OFF = 0;                                  // 512 KB
    const size_t PACKC_OFF = (size_t)NB * NN * 32 * 4;           // +512 KB
    const size_t HT_OFF    = PACKC_OFF + (size_t)NB * NN * 32 * 4;
    const size_t W_OFF     = HT_OFF + (size_t)NB * DD * NN * 2;  // +512 KB
    const size_t NEED      = W_OFF + (size_t)2 * DD * 256 * 2;   // +64 KB

    if (ws_size < NEED) {   // scratch too small: proven-correct R1 path
        msg_kernel<<<NB * NN / 4, 256, 0, stream>>>(node_state, adj_mat, matrix_in,
                                                    matrix_out, bias, out);
        return;
    }
    unsigned int*   packR = (unsigned int*)((char*)d_ws + PACKR_OFF);
    unsigned int*   packC = (unsigned int*)((char*)d_ws + PACKC_OFF);
    unsigned short* HTbf  = (unsigned short*)((char*)d_ws + HT_OFF);
    unsigned short* Wbf   = (unsigned short*)((char*)d_ws + W_OFF);

    prep_kernel<<<768, 256, 0, stream>>>(node_state, adj_mat, matrix_in, matrix_out,
                                         packR, packC, HTbf, Wbf);
    msg_mfma_kernel<<<NB * NN / 8, 256, 0, stream>>>(packR, packC, HTbf, Wbf, bias, out);
}

// Round 5
// 21.106 us; speedup vs baseline: 5.7209x; 1.0445x over previous
//
#include <hip/hip_runtime.h>

#define NB 8
#define NN 512
#define DD 64
#define NCLS 4

typedef short bf16x8 __attribute__((ext_vector_type(8)));
typedef float f32x4 __attribute__((ext_vector_type(4)));

__device__ __forceinline__ unsigned short f2bf(float f) {
    unsigned int x = __builtin_bit_cast(unsigned int, f);
    x += 0x7FFFu + ((x >> 16) & 1u);      // round-to-nearest-even (finite inputs)
    return (unsigned short)(x >> 16);
}

__device__ __forceinline__ void gload_lds16(const void* g, void* lds) {
    __builtin_amdgcn_global_load_lds(
        (const __attribute__((address_space(1))) unsigned int*)g,
        (__attribute__((address_space(3))) unsigned int*)lds, 16, 0, 0);
}

// one-hot A-fragment from 16 packed 2-bit fields; rep = cls * 0x55555555
__device__ __forceinline__ bf16x8 onehot_packed(unsigned int bits, unsigned int rep) {
    unsigned int x = bits ^ rep;           // field == 0 where class matches
    unsigned int y = x | (x >> 1);
    unsigned int m = ~y & 0x55555555u;     // bit 2i = match_i
    union { unsigned int u[4]; bf16x8 v; } r;
    #pragma unroll
    for (int j = 0; j < 4; ++j) {
        unsigned int f = m >> (4 * j);
        r.u[j] = ((f & 1u) ? 0x3F80u : 0u) | ((f & 4u) ? 0x3F800000u : 0u);
    }
    return r.v;
}

// ---- fused prep: adj read ONCE -> packR+packC; h -> HTbf; M -> Wbf ----
// blocks 0..511: adj 64x64 tile -> both packs. 512..575: h transpose. 576..703: W.
__global__ __launch_bounds__(256) void prep_kernel(
    const float* __restrict__ h, const int* __restrict__ adj,
    const float* __restrict__ Min, const float* __restrict__ Mout,
    unsigned int* __restrict__ packR, unsigned int* __restrict__ packC,
    unsigned short* __restrict__ HTbf, unsigned short* __restrict__ Wbf)
{
    const int blk = blockIdx.x, t = threadIdx.x;
    if (blk < 512) {                       // adj tile: emit row-pack AND col-pack
        __shared__ int tile[64][65];
        const int b = blk >> 6, ti = blk & 63;
        const int tr = (ti >> 3) * 64, tc = (ti & 7) * 64;
        const int* src = adj + (size_t)b * NN * NN;
        #pragma unroll
        for (int i = 0; i < 16; ++i) {
            int idx = i * 256 + t, rr = idx >> 6, cc = idx & 63;
            tile[rr][cc] = src[(size_t)(tr + rr) * NN + tc + cc];
        }
        __syncthreads();
        {
            int r = t >> 2, g = t & 3;     // r: tile row (row-pack) / tile col (col-pack)
            unsigned int ur = 0, uc = 0;
            #pragma unroll
            for (int j = 0; j < 16; ++j) {
                ur |= ((unsigned int)tile[r][16 * g + j] & 3u) << (2 * j);
                uc |= ((unsigned int)tile[16 * g + j][r] & 3u) << (2 * j);
            }
            packR[((size_t)b * NN + tr + r) * 32 + (tc >> 4) + g] = ur;
            packC[((size_t)b * NN + tc + r) * 32 + (tr >> 4) + g] = uc;
        }
    } else if (blk < 576) {                // HTbf[b][e][w] = bf16(h[b][w][e]), tiled
        __shared__ float tf[64][65];
        const int bb = blk - 512, b = bb >> 3, w0 = (bb & 7) * 64;
        #pragma unroll
        for (int i = 0; i < 16; ++i) {
            int idx = i * 256 + t, w = idx >> 6, e = idx & 63;
            tf[w][e] = h[((size_t)b * NN + w0 + w) * DD + e];   // coalesced
        }
        __syncthreads();
        // 64 e-rows x 32 u32-pairs = 2048 writes = 8 iters x 256 threads.
        // (R4 bug: 16 iters with wl=t&63 read tf[128] OOB and raced neighbors.)
        #pragma unroll
        for (int i = 0; i < 8; ++i) {
            int e = 8 * i + (t >> 5), wl = t & 31;
            unsigned int lo = f2bf(tf[2 * wl][e]);
            unsigned int hi = f2bf(tf[2 * wl + 1][e]);
            *(unsigned int*)&HTbf[((size_t)b * DD + e) * NN + w0 + 2 * wl] =
                lo | (hi << 16);                                 // coalesced u32
        }
    } else {                               // Wbf[dir][d][c*64+e] = bf16(M[c][d][e])
        int idx = (blk - 576) * 256 + t;
        int dir = idx >> 14, d = (idx >> 8) & 63, k = idx & 255;
        int c = k >> 6, e = k & 63;
        const float* M = dir ? Mout : Min;
        Wbf[idx] = f2bf(M[(c * DD + d) * DD + e]);
    }
}

// ---------------- main: one-hot MFMA from packed bits ----------------
// block: (b, 8 v's). 4 waves = (dir, row-tile). K=512 in 4 chunks of 128, dbuf.
__global__ __launch_bounds__(256) void msg_mfma_kernel(
    const unsigned int* __restrict__ packR, const unsigned int* __restrict__ packC,
    const unsigned short* __restrict__ HTbf, const unsigned short* __restrict__ Wbf,
    const float* __restrict__ bias, float* __restrict__ out)
{
    __shared__ unsigned short HT[2][DD][128];      // 2 x 16 KB, swizzled image
    __shared__ unsigned short S2[2][8][NCLS * DD]; // 8 KB, swizzled rows

    const int t = threadIdx.x;
    const int lane = t & 63, wv = t >> 6;
    const int dir = wv >> 1, rt = wv & 1;
    const int b = blockIdx.x >> 6;
    const int v0 = (blockIdx.x & 63) * 8;
    const int r = lane & 15, kb = lane >> 4;

    const unsigned short* HTg = HTbf + (size_t)b * DD * NN;

    auto stage = [&](int s, int c0) {
        #pragma unroll
        for (int q = 0; q < 4; ++q) {
            int L = wv * 4 + q;
            int e = 4 * L + (lane >> 4);
            int off = ((lane & 15) << 4) ^ ((e & 7) << 4);   // byte off in 256B row
            const unsigned short* src = HTg + e * NN + c0 * 128 + (off >> 1);
            gload_lds16(src, &HT[s][4 * L][0]);
        }
    };

    stage(0, 0);

    // A-operand bits: lane covers (vloc, cls); u16 per (chunk, kc) = 8 edges
    const int vloc = rt * 4 + (r >> 2);
    const unsigned int rep = (unsigned int)(r & 3) * 0x55555555u;
    const unsigned short* prow = (const unsigned short*)(
        (dir ? packC : packR) + ((size_t)b * NN + v0 + vloc) * 32);
    unsigned int bits0  = prow[kb];        unsigned int bits1  = prow[4 + kb];
    unsigned int bits2  = prow[8 + kb];    unsigned int bits3  = prow[12 + kb];
    unsigned int bits4  = prow[16 + kb];   unsigned int bits5  = prow[20 + kb];
    unsigned int bits6  = prow[24 + kb];   unsigned int bits7  = prow[28 + kb];
    unsigned int bits8  = prow[32 + kb];   unsigned int bits9  = prow[36 + kb];
    unsigned int bits10 = prow[40 + kb];   unsigned int bits11 = prow[44 + kb];
    unsigned int bits12 = prow[48 + kb];   unsigned int bits13 = prow[52 + kb];
    unsigned int bits14 = prow[56 + kb];   unsigned int bits15 = prow[60 + kb];

    __syncthreads();

    // ---- phase 1: S[(v,c),e] = sum_w onehot * h ----
    f32x4 acc[4] = {f32x4{0,0,0,0}, f32x4{0,0,0,0}, f32x4{0,0,0,0}, f32x4{0,0,0,0}};
    #pragma unroll
    for (int c = 0; c < 4; ++c) {
        int s = c & 1;
        if (c < 3) stage(s ^ 1, c + 1);   // prefetch next chunk (overlaps MFMA)
        #pragma unroll
        for (int kc = 0; kc < 4; ++kc) {
            unsigned int bits;
            switch (c * 4 + kc) {         // compile-time after unroll
                case 0:  bits = bits0;  break;  case 1:  bits = bits1;  break;
                case 2:  bits = bits2;  break;  case 3:  bits = bits3;  break;
                case 4:  bits = bits4;  break;  case 5:  bits = bits5;  break;
                case 6:  bits = bits6;  break;  case 7:  bits = bits7;  break;
                case 8:  bits = bits8;  break;  case 9:  bits = bits9;  break;
                case 10: bits = bits10; break;  case 11: bits = bits11; break;
                case 12: bits = bits12; break;  case 13: bits = bits13; break;
                case 14: bits = bits14; break;  default: bits = bits15; break;
            }
            bf16x8 afrag = onehot_packed(bits, rep);
            #pragma unroll
            for (int n = 0; n < 4; ++n) {
                int e = n * 16 + r;
                int boff = (kc * 64 + (kb << 4)) ^ ((e & 7) << 4);
                bf16x8 bfrag = *(const bf16x8*)((const char*)&HT[s][e][0] + boff);
                acc[n] = __builtin_amdgcn_mfma_f32_16x16x32_bf16(afrag, bfrag, acc[n], 0, 0, 0);
            }
        }
        __syncthreads();   // drains prefetch + protects buffer reuse
    }

    // ---- S -> LDS (bf16, XOR-swizzled rows). D layout: col=lane&15, row=kb*4+reg ----
    #pragma unroll
    for (int ct = 0; ct < 4; ++ct) {
        #pragma unroll
        for (int rg = 0; rg < 4; ++rg) {
            int row_g = rt * 16 + kb * 4 + rg;        // 0..31 = (v,c)
            int vv = row_g >> 2, cc2 = row_g & 3;
            int e = ct * 16 + r;
            int rb = (cc2 * 128 + e * 2) ^ ((vv & 7) << 4);
            *(unsigned short*)((char*)&S2[dir][vv][0] + rb) = f2bf(acc[ct][rg]);
        }
    }
    __syncthreads();

    // ---- phase 2: out[v, dir*64+d] = sum_{c,e} S[v,(c,e)] * W[(c,e),d] + bias ----
    f32x4 acc2[2] = {f32x4{0,0,0,0}, f32x4{0,0,0,0}};
    #pragma unroll
    for (int kc = 0; kc < 8; ++kc) {
        int vv = r & 7;                               // A rows 8..15 duplicate 0..7
        int kbase = kc * 32 + kb * 8;
        int rb = (kbase * 2) ^ (vv << 4);
        bf16x8 a2 = *(const bf16x8*)((const char*)&S2[dir][vv][0] + rb);
        #pragma unroll
        for (int j = 0; j < 2; ++j) {
            int d = (rt * 2 + j) * 16 + r;
            bf16x8 b2 = *(const bf16x8*)&Wbf[(dir * DD + d) * 256 + kbase];
            acc2[j] = __builtin_amdgcn_mfma_f32_16x16x32_bf16(a2, b2, acc2[j], 0, 0, 0);
        }
    }
    #pragma unroll
    for (int j = 0; j < 2; ++j) {
        int d = (rt * 2 + j) * 16 + r;
        float bs = bias[dir * DD + d];
        #pragma unroll
        for (int rg = 0; rg < 4; ++rg) {
            int row = kb * 4 + rg;                    // duplicated rows >=8 skipped
            if (row < 8)
                out[((size_t)(b * NN + v0 + row)) * (2 * DD) + dir * DD + d] = acc2[j][rg] + bs;
        }
    }
}

// ---------------- fallback (R1 kernel, used only if ws too small) ----------------
__global__ __launch_bounds__(256) void msg_kernel(
    const float* __restrict__ h, const int* __restrict__ adj,
    const float* __restrict__ Min, const float* __restrict__ Mout,
    const float* __restrict__ bias, float* __restrict__ out)
{
    __shared__ __align__(16) float S[4][2][NCLS][DD];
    const int lane = threadIdx.x & 63, wslot = threadIdx.x >> 6;
    const int wid = blockIdx.x * 4 + wslot;
    const int b = wid >> 9, v = wid & (NN - 1);
    const float* hb = h + (size_t)b * NN * DD;
    const int* adjb = adj + (size_t)b * NN * NN;
    float tot = 0.f, ain1 = 0.f, ain2 = 0.f, ain3 = 0.f, aout1 = 0.f, aout2 = 0.f, aout3 = 0.f;
    for (int w0 = 0; w0 < NN; w0 += 64) {
        int cin_chunk = adjb[v * NN + (w0 + lane)];
        int cout_chunk = adjb[(w0 + lane) * NN + v];
        #pragma unroll
        for (int k = 0; k < 64; ++k) {
            float hw = hb[(w0 + k) * DD + lane];
            int cin = __builtin_amdgcn_readlane(cin_chunk, k);
            int cout = __builtin_amdgcn_readlane(cout_chunk, k);
            tot += hw;
            ain1 = fmaf((cin == 1) ? 1.f : 0.f, hw, ain1);
            ain2 = fmaf((cin == 2) ? 1.f : 0.f, hw, ain2);
            ain3 = fmaf((cin == 3) ? 1.f : 0.f, hw, ain3);
            aout1 = fmaf((cout == 1) ? 1.f : 0.f, hw, aout1);
            aout2 = fmaf((cout == 2) ? 1.f : 0.f, hw, aout2);
            aout3 = fmaf((cout == 3) ? 1.f : 0.f, hw, aout3);
        }
    }
    S[wslot][0][0][lane] = tot - ain1 - ain2 - ain3;
    S[wslot][0][1][lane] = ain1; S[wslot][0][2][lane] = ain2; S[wslot][0][3][lane] = ain3;
    S[wslot][1][0][lane] = tot - aout1 - aout2 - aout3;
    S[wslot][1][1][lane] = aout1; S[wslot][1][2][lane] = aout2; S[wslot][1][3][lane] = aout3;
    __syncthreads();
    float o_in = 0.f, o_out = 0.f;
    #pragma unroll
    for (int c = 0; c < NCLS; ++c)
        for (int e0 = 0; e0 < DD; e0 += 4) {
            float4 mi = *reinterpret_cast<const float4*>(&Min[(c * DD + lane) * DD + e0]);
            float4 mo = *reinterpret_cast<const float4*>(&Mout[(c * DD + lane) * DD + e0]);
            float4 si = *reinterpret_cast<const float4*>(&S[wslot][0][c][e0]);
            float4 so = *reinterpret_cast<const float4*>(&S[wslot][1][c][e0]);
            o_in = fmaf(mi.x, si.x, fmaf(mi.y, si.y, fmaf(mi.z, si.z, fmaf(mi.w, si.w, o_in))));
            o_out = fmaf(mo.x, so.x, fmaf(mo.y, so.y, fmaf(mo.z, so.z, fmaf(mo.w, so.w, o_out))));
        }
    float* ov = out + (size_t)(b * NN + v) * (2 * DD);
    ov[lane] = o_in + bias[lane];
    ov[DD + lane] = o_out + bias[DD + lane];
}

extern "C" void kernel_launch(void* const* d_in, const int* in_sizes, int n_in,
                              void* d_out, int out_size, void* d_ws, size_t ws_size,
                              hipStream_t stream) {
    const float* node_state = (const float*)d_in[0];
    const int*   adj_mat    = (const int*)  d_in[1];
    const float* matrix_in  = (const float*)d_in[2];
    const float* matrix_out = (const float*)d_in[3];
    const float* bias       = (const float*)d_in[4];
    float* out = (float*)d_out;

    const size_t PACKR_OFF = 0;                                  // 512 KB
    const size_t PACKC_OFF = (size_t)NB * NN * 32 * 4;           // +512 KB
    const size_t HT_OFF    = PACKC_OFF + (size_t)NB * NN * 32 * 4;
    const size_t W_OFF     = HT_OFF + (size_t)NB * DD * NN * 2;  // +512 KB
    const size_t NEED      = W_OFF + (size_t)2 * DD * 256 * 2;   // +64 KB

    if (ws_size < NEED) {   // scratch too small: proven-correct R1 path
        msg_kernel<<<NB * NN / 4, 256, 0, stream>>>(node_state, adj_mat, matrix_in,
                                                    matrix_out, bias, out);
        return;
    }
    unsigned int*   packR = (unsigned int*)((char*)d_ws + PACKR_OFF);
    unsigned int*   packC = (unsigned int*)((char*)d_ws + PACKC_OFF);
    unsigned short* HTbf  = (unsigned short*)((char*)d_ws + HT_OFF);
    unsigned short* Wbf   = (unsigned short*)((char*)d_ws + W_OFF);

    prep_kernel<<<704, 256, 0, stream>>>(node_state, adj_mat, matrix_in, matrix_out,
                                         packR, packC, HTbf, Wbf);
    msg_mfma_kernel<<<NB * NN / 8, 256, 0, stream>>>(packR, packC, HTbf, Wbf, bias, out);
}

// Round 6
// 20.278 us; speedup vs baseline: 5.9546x; 1.0408x over previous
//
#include <hip/hip_runtime.h>

#define NB 8
#define NN 512
#define DD 64
#define NCLS 4

typedef short bf16x8 __attribute__((ext_vector_type(8)));
typedef float f32x4 __attribute__((ext_vector_type(4)));

__device__ __forceinline__ unsigned short f2bf(float f) {
    unsigned int x = __builtin_bit_cast(unsigned int, f);
    x += 0x7FFFu + ((x >> 16) & 1u);      // round-to-nearest-even (finite inputs)
    return (unsigned short)(x >> 16);
}

__device__ __forceinline__ void gload_lds16(const void* g, void* lds) {
    __builtin_amdgcn_global_load_lds(
        (const __attribute__((address_space(1))) unsigned int*)g,
        (__attribute__((address_space(3))) unsigned int*)lds, 16, 0, 0);
}

// one-hot A-fragment from 16 packed 2-bit fields; rep = cls * 0x55555555
__device__ __forceinline__ bf16x8 onehot_packed(unsigned int bits, unsigned int rep) {
    unsigned int x = bits ^ rep;           // field == 0 where class matches
    unsigned int y = x | (x >> 1);
    unsigned int m = ~y & 0x55555555u;     // bit 2i = match_i
    union { unsigned int u[4]; bf16x8 v; } r;
    #pragma unroll
    for (int j = 0; j < 4; ++j) {
        unsigned int f = m >> (4 * j);
        r.u[j] = ((f & 1u) ? 0x3F80u : 0u) | ((f & 4u) ? 0x3F800000u : 0u);
    }
    return r.v;
}

// ---- fused prep: adj read ONCE -> packR+packC; h -> HTbf; M -> Wbf ----
// blocks 0..511: adj 64x64 tile -> both packs. 512..575: h transpose. 576..703: W.
__global__ __launch_bounds__(256) void prep_kernel(
    const float* __restrict__ h, const int* __restrict__ adj,
    const float* __restrict__ Min, const float* __restrict__ Mout,
    unsigned int* __restrict__ packR, unsigned int* __restrict__ packC,
    unsigned short* __restrict__ HTbf, unsigned short* __restrict__ Wbf)
{
    const int blk = blockIdx.x, t = threadIdx.x;
    if (blk < 512) {                       // adj tile: emit row-pack AND col-pack
        __shared__ int tile[64][65];
        const int b = blk >> 6, ti = blk & 63;
        const int tr = (ti >> 3) * 64, tc = (ti & 7) * 64;
        const int* src = adj + (size_t)b * NN * NN;
        #pragma unroll
        for (int i = 0; i < 16; ++i) {
            int idx = i * 256 + t, rr = idx >> 6, cc = idx & 63;
            tile[rr][cc] = src[(size_t)(tr + rr) * NN + tc + cc];
        }
        __syncthreads();
        {
            int r = t >> 2, g = t & 3;     // r: tile row (row-pack) / tile col (col-pack)
            unsigned int ur = 0, uc = 0;
            #pragma unroll
            for (int j = 0; j < 16; ++j) {
                ur |= ((unsigned int)tile[r][16 * g + j] & 3u) << (2 * j);
                uc |= ((unsigned int)tile[16 * g + j][r] & 3u) << (2 * j);
            }
            packR[((size_t)b * NN + tr + r) * 32 + (tc >> 4) + g] = ur;
            packC[((size_t)b * NN + tc + r) * 32 + (tr >> 4) + g] = uc;
        }
    } else if (blk < 576) {                // HTbf[b][e][w] = bf16(h[b][w][e]), tiled
        __shared__ float tf[64][65];
        const int bb = blk - 512, b = bb >> 3, w0 = (bb & 7) * 64;
        #pragma unroll
        for (int i = 0; i < 16; ++i) {
            int idx = i * 256 + t, w = idx >> 6, e = idx & 63;
            tf[w][e] = h[((size_t)b * NN + w0 + w) * DD + e];   // coalesced
        }
        __syncthreads();
        // 64 e-rows x 32 u32-pairs = 2048 writes = 8 iters x 256 threads
        #pragma unroll
        for (int i = 0; i < 8; ++i) {
            int e = 8 * i + (t >> 5), wl = t & 31;
            unsigned int lo = f2bf(tf[2 * wl][e]);
            unsigned int hi = f2bf(tf[2 * wl + 1][e]);
            *(unsigned int*)&HTbf[((size_t)b * DD + e) * NN + w0 + 2 * wl] =
                lo | (hi << 16);                                 // coalesced u32
        }
    } else {                               // Wbf[dir][d][c*64+e] = bf16(M[c][d][e])
        int idx = (blk - 576) * 256 + t;
        int dir = idx >> 14, d = (idx >> 8) & 63, k = idx & 255;
        int c = k >> 6, e = k & 63;
        const float* M = dir ? Mout : Min;
        Wbf[idx] = f2bf(M[(c * DD + d) * DD + e]);
    }
}

// ---------------- main: one-hot MFMA, full-prefetch single-barrier ----------------
// block: (b, 8 v's). 4 waves = (dir, row-tile). ALL of K=512 staged once (64 KB).
__global__ __launch_bounds__(256) void msg_mfma_kernel(
    const unsigned int* __restrict__ packR, const unsigned int* __restrict__ packC,
    const unsigned short* __restrict__ HTbf, const unsigned short* __restrict__ Wbf,
    const float* __restrict__ bias, float* __restrict__ out)
{
    __shared__ unsigned short HT[4][DD][128];      // 4 chunks x 16 KB, swizzled image
    __shared__ unsigned short S2[2][8][NCLS * DD]; // 8 KB, swizzled rows

    const int t = threadIdx.x;
    const int lane = t & 63, wv = t >> 6;
    const int dir = wv >> 1, rt = wv & 1;
    const int b = blockIdx.x >> 6;
    const int v0 = (blockIdx.x & 63) * 8;
    const int r = lane & 15, kb = lane >> 4;

    const unsigned short* HTg = HTbf + (size_t)b * DD * NN;

    // ---- issue ALL staging up-front: 16 gload_lds per wave, one latency exposure ----
    #pragma unroll
    for (int c0 = 0; c0 < 4; ++c0) {
        #pragma unroll
        for (int q = 0; q < 4; ++q) {
            int L = wv * 4 + q;
            int e = 4 * L + (lane >> 4);
            int off = ((lane & 15) << 4) ^ ((e & 7) << 4);   // byte off in 256B row
            const unsigned short* src = HTg + e * NN + c0 * 128 + (off >> 1);
            gload_lds16(src, &HT[c0][4 * L][0]);
        }
    }

    // A-operand bits overlap the staging latency: lane covers (vloc, cls)
    const int vloc = rt * 4 + (r >> 2);
    const unsigned int rep = (unsigned int)(r & 3) * 0x55555555u;
    const unsigned short* prow = (const unsigned short*)(
        (dir ? packC : packR) + ((size_t)b * NN + v0 + vloc) * 32);
    unsigned int bits0  = prow[kb];        unsigned int bits1  = prow[4 + kb];
    unsigned int bits2  = prow[8 + kb];    unsigned int bits3  = prow[12 + kb];
    unsigned int bits4  = prow[16 + kb];   unsigned int bits5  = prow[20 + kb];
    unsigned int bits6  = prow[24 + kb];   unsigned int bits7  = prow[28 + kb];
    unsigned int bits8  = prow[32 + kb];   unsigned int bits9  = prow[36 + kb];
    unsigned int bits10 = prow[40 + kb];   unsigned int bits11 = prow[44 + kb];
    unsigned int bits12 = prow[48 + kb];   unsigned int bits13 = prow[52 + kb];
    unsigned int bits14 = prow[56 + kb];   unsigned int bits15 = prow[60 + kb];

    __syncthreads();   // ONE barrier: drains all 16 loads, all waves aligned

    // ---- phase 1: S[(v,c),e] = sum_w onehot * h — barrier-free MFMA stream ----
    f32x4 acc[4] = {f32x4{0,0,0,0}, f32x4{0,0,0,0}, f32x4{0,0,0,0}, f32x4{0,0,0,0}};
    #pragma unroll
    for (int c = 0; c < 4; ++c) {
        #pragma unroll
        for (int kc = 0; kc < 4; ++kc) {
            unsigned int bits;
            switch (c * 4 + kc) {         // compile-time after unroll
                case 0:  bits = bits0;  break;  case 1:  bits = bits1;  break;
                case 2:  bits = bits2;  break;  case 3:  bits = bits3;  break;
                case 4:  bits = bits4;  break;  case 5:  bits = bits5;  break;
                case 6:  bits = bits6;  break;  case 7:  bits = bits7;  break;
                case 8:  bits = bits8;  break;  case 9:  bits = bits9;  break;
                case 10: bits = bits10; break;  case 11: bits = bits11; break;
                case 12: bits = bits12; break;  case 13: bits = bits13; break;
                case 14: bits = bits14; break;  default: bits = bits15; break;
            }
            bf16x8 afrag = onehot_packed(bits, rep);
            #pragma unroll
            for (int n = 0; n < 4; ++n) {
                int e = n * 16 + r;
                int boff = (kc * 64 + (kb << 4)) ^ ((e & 7) << 4);
                bf16x8 bfrag = *(const bf16x8*)((const char*)&HT[c][e][0] + boff);
                acc[n] = __builtin_amdgcn_mfma_f32_16x16x32_bf16(afrag, bfrag, acc[n], 0, 0, 0);
            }
        }
    }

    // ---- S -> LDS (bf16, XOR-swizzled rows). D layout: col=lane&15, row=kb*4+reg ----
    #pragma unroll
    for (int ct = 0; ct < 4; ++ct) {
        #pragma unroll
        for (int rg = 0; rg < 4; ++rg) {
            int row_g = rt * 16 + kb * 4 + rg;        // 0..31 = (v,c)
            int vv = row_g >> 2, cc2 = row_g & 3;
            int e = ct * 16 + r;
            int rb = (cc2 * 128 + e * 2) ^ ((vv & 7) << 4);
            *(unsigned short*)((char*)&S2[dir][vv][0] + rb) = f2bf(acc[ct][rg]);
        }
    }
    __syncthreads();

    // ---- phase 2: out[v, dir*64+d] = sum_{c,e} S[v,(c,e)] * W[(c,e),d] + bias ----
    f32x4 acc2[2] = {f32x4{0,0,0,0}, f32x4{0,0,0,0}};
    #pragma unroll
    for (int kc = 0; kc < 8; ++kc) {
        int vv = r & 7;                               // A rows 8..15 duplicate 0..7
        int kbase = kc * 32 + kb * 8;
        int rb = (kbase * 2) ^ (vv << 4);
        bf16x8 a2 = *(const bf16x8*)((const char*)&S2[dir][vv][0] + rb);
        #pragma unroll
        for (int j = 0; j < 2; ++j) {
            int d = (rt * 2 + j) * 16 + r;
            bf16x8 b2 = *(const bf16x8*)&Wbf[(dir * DD + d) * 256 + kbase];
            acc2[j] = __builtin_amdgcn_mfma_f32_16x16x32_bf16(a2, b2, acc2[j], 0, 0, 0);
        }
    }
    #pragma unroll
    for (int j = 0; j < 2; ++j) {
        int d = (rt * 2 + j) * 16 + r;
        float bs = bias[dir * DD + d];
        #pragma unroll
        for (int rg = 0; rg < 4; ++rg) {
            int row = kb * 4 + rg;                    // duplicated rows >=8 skipped
            if (row < 8)
                out[((size_t)(b * NN + v0 + row)) * (2 * DD) + dir * DD + d] = acc2[j][rg] + bs;
        }
    }
}

// ---------------- fallback (R1 kernel, used only if ws too small) ----------------
__global__ __launch_bounds__(256) void msg_kernel(
    const float* __restrict__ h, const int* __restrict__ adj,
    const float* __restrict__ Min, const float* __restrict__ Mout,
    const float* __restrict__ bias, float* __restrict__ out)
{
    __shared__ __align__(16) float S[4][2][NCLS][DD];
    const int lane = threadIdx.x & 63, wslot = threadIdx.x >> 6;
    const int wid = blockIdx.x * 4 + wslot;
    const int b = wid >> 9, v = wid & (NN - 1);
    const float* hb = h + (size_t)b * NN * DD;
    const int* adjb = adj + (size_t)b * NN * NN;
    float tot = 0.f, ain1 = 0.f, ain2 = 0.f, ain3 = 0.f, aout1 = 0.f, aout2 = 0.f, aout3 = 0.f;
    for (int w0 = 0; w0 < NN; w0 += 64) {
        int cin_chunk = adjb[v * NN + (w0 + lane)];
        int cout_chunk = adjb[(w0 + lane) * NN + v];
        #pragma unroll
        for (int k = 0; k < 64; ++k) {
            float hw = hb[(w0 + k) * DD + lane];
            int cin = __builtin_amdgcn_readlane(cin_chunk, k);
            int cout = __builtin_amdgcn_readlane(cout_chunk, k);
            tot += hw;
            ain1 = fmaf((cin == 1) ? 1.f : 0.f, hw, ain1);
            ain2 = fmaf((cin == 2) ? 1.f : 0.f, hw, ain2);
            ain3 = fmaf((cin == 3) ? 1.f : 0.f, hw, ain3);
            aout1 = fmaf((cout == 1) ? 1.f : 0.f, hw, aout1);
            aout2 = fmaf((cout == 2) ? 1.f : 0.f, hw, aout2);
            aout3 = fmaf((cout == 3) ? 1.f : 0.f, hw, aout3);
        }
    }
    S[wslot][0][0][lane] = tot - ain1 - ain2 - ain3;
    S[wslot][0][1][lane] = ain1; S[wslot][0][2][lane] = ain2; S[wslot][0][3][lane] = ain3;
    S[wslot][1][0][lane] = tot - aout1 - aout2 - aout3;
    S[wslot][1][1][lane] = aout1; S[wslot][1][2][lane] = aout2; S[wslot][1][3][lane] = aout3;
    __syncthreads();
    float o_in = 0.f, o_out = 0.f;
    #pragma unroll
    for (int c = 0; c < NCLS; ++c)
        for (int e0 = 0; e0 < DD; e0 += 4) {
            float4 mi = *reinterpret_cast<const float4*>(&Min[(c * DD + lane) * DD + e0]);
            float4 mo = *reinterpret_cast<const float4*>(&Mout[(c * DD + lane) * DD + e0]);
            float4 si = *reinterpret_cast<const float4*>(&S[wslot][0][c][e0]);
            float4 so = *reinterpret_cast<const float4*>(&S[wslot][1][c][e0]);
            o_in = fmaf(mi.x, si.x, fmaf(mi.y, si.y, fmaf(mi.z, si.z, fmaf(mi.w, si.w, o_in))));
            o_out = fmaf(mo.x, so.x, fmaf(mo.y, so.y, fmaf(mo.z, so.z, fmaf(mo.w, so.w, o_out))));
        }
    float* ov = out + (size_t)(b * NN + v) * (2 * DD);
    ov[lane] = o_in + bias[lane];
    ov[DD + lane] = o_out + bias[DD + lane];
}

extern "C" void kernel_launch(void* const* d_in, const int* in_sizes, int n_in,
                              void* d_out, int out_size, void* d_ws, size_t ws_size,
                              hipStream_t stream) {
    const float* node_state = (const float*)d_in[0];
    const int*   adj_mat    = (const int*)  d_in[1];
    const float* matrix_in  = (const float*)d_in[2];
    const float* matrix_out = (const float*)d_in[3];
    const float* bias       = (const float*)d_in[4];
    float* out = (float*)d_out;

    const size_t PACKR_OFF = 0;                                  // 512 KB
    const size_t PACKC_OFF = (size_t)NB * NN * 32 * 4;           // +512 KB
    const size_t HT_OFF    = PACKC_OFF + (size_t)NB * NN * 32 * 4;
    const size_t W_OFF     = HT_OFF + (size_t)NB * DD * NN * 2;  // +512 KB
    const size_t NEED      = W_OFF + (size_t)2 * DD * 256 * 2;   // +64 KB

    if (ws_size < NEED) {   // scratch too small: proven-correct R1 path
        msg_kernel<<<NB * NN / 4, 256, 0, stream>>>(node_state, adj_mat, matrix_in,
                                                    matrix_out, bias, out);
        return;
    }
    unsigned int*   packR = (unsigned int*)((char*)d_ws + PACKR_OFF);
    unsigned int*   packC = (unsigned int*)((char*)d_ws + PACKC_OFF);
    unsigned short* HTbf  = (unsigned short*)((char*)d_ws + HT_OFF);
    unsigned short* Wbf   = (unsigned short*)((char*)d_ws + W_OFF);

    prep_kernel<<<704, 256, 0, stream>>>(node_state, adj_mat, matrix_in, matrix_out,
                                         packR, packC, HTbf, Wbf);
    msg_mfma_kernel<<<NB * NN / 8, 256, 0, stream>>>(packR, packC, HTbf, Wbf, bias, out);
}